// Round 1
// baseline (1658.238 us; speedup 1.0000x reference)
//
#include <hip/hip_runtime.h>

constexpr int DD = 128;   // hidden dim D
constexpr int AA = 64;    // attention dim A
constexpr int GG = 384;   // 3*D (GRU gates)

#define SLOPE_F 0.22916666666666666f
#define LNEPS   1e-5f

static __device__ __forceinline__ float wave_sum(float v){
#pragma unroll
  for (int off = 32; off > 0; off >>= 1) v += __shfl_xor(v, off, 64);
  return v;
}
static __device__ __forceinline__ float sigm(float x){ return 1.0f / (1.0f + __expf(-x)); }
static __device__ __forceinline__ float rrelu_f(float x){ return x >= 0.0f ? x : SLOPE_F * x; }

// ---- transpose [K,128] -> [128,K] (GRU weights, PyTorch layout -> coalesced)
__global__ void __launch_bounds__(256) k_transpose(const float* __restrict__ w, float* __restrict__ wT, int K){
  int tid = blockIdx.x * blockDim.x + threadIdx.x;
  if (tid < K * DD){
    int k = tid / DD, d = tid - k * DD;
    wT[(size_t)d * K + k] = w[(size_t)k * DD + d];
  }
}

// ---- rel = LN(rel + relu(rel @ rtw + rtb)); one row per wave, in place
__global__ void __launch_bounds__(256) k_rel_transfer(float* __restrict__ rel,
    const float* __restrict__ rtw, const float* __restrict__ rtb,
    const float* __restrict__ g, const float* __restrict__ b, int rows){
  const int lane = threadIdx.x & 63;
  int wave = (int)((blockIdx.x * blockDim.x + threadIdx.x) >> 6);
  if (wave >= rows) return;
  int row = __builtin_amdgcn_readfirstlane(wave);
  const float* x = rel + (size_t)row * DD;
  float y0 = 0.f, y1 = 0.f;
#pragma unroll 4
  for (int d = 0; d < DD; ++d){
    float xd = x[d];
    y0 = fmaf(xd, rtw[d*DD + lane],      y0);
    y1 = fmaf(xd, rtw[d*DD + 64 + lane], y1);
  }
  float t0 = x[lane]      + fmaxf(y0 + rtb[lane],      0.f);
  float t1 = x[64 + lane] + fmaxf(y1 + rtb[64 + lane], 0.f);
  float mu = wave_sum(t0 + t1) * (1.0f/128.0f);
  float e0 = t0 - mu, e1 = t1 - mu;
  float var = wave_sum(e0*e0 + e1*e1) * (1.0f/128.0f);
  float rs = rsqrtf(var + LNEPS);
  float* o = rel + (size_t)row * DD;
  o[lane]      = e0 * rs * g[lane]      + b[lane];
  o[64 + lane] = e1 * rs * g[64 + lane] + b[64 + lane];
}

// ---- in-place LayerNorm of rows (step 12)
__global__ void __launch_bounds__(256) k_ln_rows(float* __restrict__ X,
    const float* __restrict__ g, const float* __restrict__ b, int rows){
  const int lane = threadIdx.x & 63;
  int wave = (int)((blockIdx.x * blockDim.x + threadIdx.x) >> 6);
  if (wave >= rows) return;
  int row = __builtin_amdgcn_readfirstlane(wave);
  float* x = X + (size_t)row * DD;
  float t0 = x[lane], t1 = x[64 + lane];
  float mu = wave_sum(t0 + t1) * (1.0f/128.0f);
  float e0 = t0 - mu, e1 = t1 - mu;
  float var = wave_sum(e0*e0 + e1*e1) * (1.0f/128.0f);
  float rs = rsqrtf(var + LNEPS);
  x[lane]      = e0 * rs * g[lane]      + b[lane];
  x[64 + lane] = e1 * rs * g[64 + lane] + b[64 + lane];
}

// ---- Y[rows,64] = X[rows,128] @ W[128,64]; 4 rows per wave (weight reuse x4)
__global__ void __launch_bounds__(256) k_proj4(const float* __restrict__ X,
    const float* __restrict__ W, float* __restrict__ Y, int rows){
  const int lane = threadIdx.x & 63;
  int wave = (int)((blockIdx.x * blockDim.x + threadIdx.x) >> 6);
  int r0 = wave * 4;
  if (r0 >= rows) return;
  r0 = __builtin_amdgcn_readfirstlane(r0);
  const int rl = rows - 1;
  const float* x0 = X + (size_t)r0 * DD;
  const float* x1 = X + (size_t)min(r0+1, rl) * DD;
  const float* x2 = X + (size_t)min(r0+2, rl) * DD;
  const float* x3 = X + (size_t)min(r0+3, rl) * DD;
  float a0=0.f, a1=0.f, a2=0.f, a3=0.f;
#pragma unroll 4
  for (int d = 0; d < DD; ++d){
    float w = W[d*AA + lane];
    a0 = fmaf(x0[d], w, a0);
    a1 = fmaf(x1[d], w, a1);
    a2 = fmaf(x2[d], w, a2);
    a3 = fmaf(x3[d], w, a3);
  }
  Y[(size_t)r0*AA + lane] = a0;
  if (r0+1 < rows) Y[(size_t)(r0+1)*AA + lane] = a1;
  if (r0+2 < rows) Y[(size_t)(r0+2)*AA + lane] = a2;
  if (r0+3 < rows) Y[(size_t)(r0+3)*AA + lane] = a3;
}

// ---- qr[b,:] = rel[q_rel[b]+b*Rp1,:] @ Wqr + bias   (B rows, one per wave)
__global__ void __launch_bounds__(256) k_projq(const float* __restrict__ rel,
    const float* __restrict__ Wqr, const float* __restrict__ bias,
    const int* __restrict__ q_rel, float* __restrict__ out, int Bc, int Rp1){
  const int lane = threadIdx.x & 63;
  int wave = (int)((blockIdx.x * blockDim.x + threadIdx.x) >> 6);
  if (wave >= Bc) return;
  int b = __builtin_amdgcn_readfirstlane(wave);
  int f = __builtin_amdgcn_readfirstlane(q_rel[b] + b * Rp1);
  const float* x = rel + (size_t)f * DD;
  float a = 0.f;
#pragma unroll 4
  for (int d = 0; d < DD; ++d) a = fmaf(x[d], Wqr[d*AA + lane], a);
  out[(size_t)b*AA + lane] = a + bias[lane];
}

// ---- edge kernel: one edge per wave; alpha + scatter-add of msg into agg
__global__ void __launch_bounds__(256) k_edge(const float* __restrict__ hid,
    const float* __restrict__ relE, const float* __restrict__ hsW,
    const float* __restrict__ hrW, const float* __restrict__ qr,
    const float* __restrict__ wal, const float* __restrict__ walb_p,
    const int* __restrict__ sub, const int* __restrict__ obj,
    const int* __restrict__ bidx, const int* __restrict__ reli,
    float* __restrict__ agg, int E, int Rp1){
  const int lane = threadIdx.x & 63;
  const int wpb = blockDim.x >> 6;
  int w0 = blockIdx.x * wpb + (threadIdx.x >> 6);
  const int stride = gridDim.x * wpb;
  const float wa = wal[lane];
  const float wb = walb_p[0];
  for (int e = w0; e < E; e += stride){
    int eu = __builtin_amdgcn_readfirstlane(e);
    int s  = sub[eu];
    int o  = obj[eu];
    int bb = bidx[eu];
    int f  = reli[eu] + bb * Rp1;
    float pre = hsW[(size_t)s*AA + lane] + hrW[(size_t)f*AA + lane] + qr[(size_t)bb*AA + lane];
    float t = rrelu_f(pre);
    float al = sigm(wave_sum(t * wa) + wb);
    float hs0 = hid[(size_t)s*DD + lane],  hs1 = hid[(size_t)s*DD + 64 + lane];
    float hr0 = relE[(size_t)f*DD + lane], hr1 = relE[(size_t)f*DD + 64 + lane];
    unsafeAtomicAdd(&agg[(size_t)o*DD + lane],      al * (hs0 + hr0));
    unsafeAtomicAdd(&agg[(size_t)o*DD + 64 + lane], al * (hs1 + hr1));
  }
}

// ---- X = LN(rrelu(X @ Wm)) ; 4 rows per wave, in-place
__global__ void __launch_bounds__(256) k_wh_ln(float* __restrict__ X,
    const float* __restrict__ Wm, const float* __restrict__ g,
    const float* __restrict__ b, int rows){
  const int lane = threadIdx.x & 63;
  int wave = (int)((blockIdx.x * blockDim.x + threadIdx.x) >> 6);
  int r0 = wave * 4;
  if (r0 >= rows) return;
  r0 = __builtin_amdgcn_readfirstlane(r0);
  const int rl = rows - 1;
  const float* x0 = X + (size_t)r0 * DD;
  const float* x1 = X + (size_t)min(r0+1, rl) * DD;
  const float* x2 = X + (size_t)min(r0+2, rl) * DD;
  const float* x3 = X + (size_t)min(r0+3, rl) * DD;
  float a00=0,a01=0,a10=0,a11=0,a20=0,a21=0,a30=0,a31=0;
#pragma unroll 2
  for (int d = 0; d < DD; ++d){
    float w0 = Wm[d*DD + lane];
    float w1 = Wm[d*DD + 64 + lane];
    float v0 = x0[d], v1 = x1[d], v2 = x2[d], v3 = x3[d];
    a00 = fmaf(v0, w0, a00); a01 = fmaf(v0, w1, a01);
    a10 = fmaf(v1, w0, a10); a11 = fmaf(v1, w1, a11);
    a20 = fmaf(v2, w0, a20); a21 = fmaf(v2, w1, a21);
    a30 = fmaf(v3, w0, a30); a31 = fmaf(v3, w1, a31);
  }
  float gl = g[lane], gh = g[64+lane], bl = b[lane], bhv = b[64+lane];
#pragma unroll
  for (int r = 0; r < 4; ++r){
    if (r0 + r < rows){
      float t0, t1;
      if      (r==0){ t0=a00; t1=a01; }
      else if (r==1){ t0=a10; t1=a11; }
      else if (r==2){ t0=a20; t1=a21; }
      else          { t0=a30; t1=a31; }
      t0 = rrelu_f(t0); t1 = rrelu_f(t1);
      float mu = wave_sum(t0 + t1) * (1.0f/128.0f);
      float e0 = t0 - mu, e1 = t1 - mu;
      float var = wave_sum(e0*e0 + e1*e1) * (1.0f/128.0f);
      float rs = rsqrtf(var + LNEPS);
      float* o = X + (size_t)(r0 + r) * DD;
      o[lane]      = e0 * rs * gl  + bl;
      o[64 + lane] = e1 * rs * gh  + bhv;
    }
  }
}

// ---- GRU step: X = gru(x=X, h=H) in-place; 4 rows per wave, 12 gate-cols per lane
__global__ void __launch_bounds__(256) k_gru4(float* __restrict__ X,
    const float* __restrict__ H, const float* __restrict__ wihT,
    const float* __restrict__ whhT, const float* __restrict__ bih,
    const float* __restrict__ bhh, int rows){
  const int lane = threadIdx.x & 63;
  int wave = (int)((blockIdx.x * blockDim.x + threadIdx.x) >> 6);
  int r0 = wave * 4;
  if (r0 >= rows) return;
  r0 = __builtin_amdgcn_readfirstlane(r0);
  const int rl = rows - 1;
  const float* x0 = X + (size_t)r0 * DD;
  const float* x1 = X + (size_t)min(r0+1, rl) * DD;
  const float* x2 = X + (size_t)min(r0+2, rl) * DD;
  const float* x3 = X + (size_t)min(r0+3, rl) * DD;
  float ai[4][6]; float ah[4][6];
#pragma unroll
  for (int r=0;r<4;++r)
#pragma unroll
    for (int m=0;m<6;++m){ ai[r][m]=0.f; ah[r][m]=0.f; }

  if (H != nullptr){
    const float* h0 = H + (size_t)r0 * DD;
    const float* h1 = H + (size_t)min(r0+1, rl) * DD;
    const float* h2 = H + (size_t)min(r0+2, rl) * DD;
    const float* h3 = H + (size_t)min(r0+3, rl) * DD;
#pragma unroll 2
    for (int d = 0; d < DD; ++d){
      float wi[6], wh[6];
#pragma unroll
      for (int m=0;m<6;++m){ wi[m] = wihT[d*GG + m*64 + lane]; wh[m] = whhT[d*GG + m*64 + lane]; }
      float xs[4] = { x0[d], x1[d], x2[d], x3[d] };
      float hs[4] = { h0[d], h1[d], h2[d], h3[d] };
#pragma unroll
      for (int r=0;r<4;++r)
#pragma unroll
        for (int m=0;m<6;++m){
          ai[r][m] = fmaf(xs[r], wi[m], ai[r][m]);
          ah[r][m] = fmaf(hs[r], wh[m], ah[r][m]);
        }
    }
  } else {
#pragma unroll 2
    for (int d = 0; d < DD; ++d){
      float wi[6];
#pragma unroll
      for (int m=0;m<6;++m) wi[m] = wihT[d*GG + m*64 + lane];
      float xs[4] = { x0[d], x1[d], x2[d], x3[d] };
#pragma unroll
      for (int r=0;r<4;++r)
#pragma unroll
        for (int m=0;m<6;++m) ai[r][m] = fmaf(xs[r], wi[m], ai[r][m]);
    }
  }
  float bi[6], bh2[6];
#pragma unroll
  for (int m=0;m<6;++m){ bi[m] = bih[m*64 + lane]; bh2[m] = bhh[m*64 + lane]; }
#pragma unroll
  for (int r=0;r<4;++r){
    if (r0 + r < rows){
#pragma unroll
      for (int hf=0; hf<2; ++hf){
        float gir = ai[r][hf]   + bi[hf];
        float giz = ai[r][2+hf] + bi[2+hf];
        float gin = ai[r][4+hf] + bi[4+hf];
        float ghr = ah[r][hf]   + bh2[hf];
        float ghz = ah[r][2+hf] + bh2[2+hf];
        float ghn = ah[r][4+hf] + bh2[4+hf];
        float rg = sigm(gir + ghr);
        float zg = sigm(giz + ghz);
        float ng = tanhf(gin + rg * ghn);
        float hp = 0.f;
        if (H != nullptr) hp = H[(size_t)(r0 + r) * DD + hf*64 + lane];
        X[(size_t)(r0 + r) * DD + hf*64 + lane] = (1.f - zg) * ng + zg * hp;
      }
    }
  }
}

// ---- scores = H @ wf ; record max-index winner per (batch,ent) slot
__global__ void __launch_bounds__(256) k_score(const float* __restrict__ Hf,
    const float* __restrict__ wf, const int* __restrict__ nb, const int* __restrict__ ne,
    float* __restrict__ scores, int* __restrict__ winner, int rows, int NENT){
  const int lane = threadIdx.x & 63;
  int wave = (int)((blockIdx.x * blockDim.x + threadIdx.x) >> 6);
  if (wave >= rows) return;
  int row = __builtin_amdgcn_readfirstlane(wave);
  float v = Hf[(size_t)row*DD + lane] * wf[lane] + Hf[(size_t)row*DD + 64 + lane] * wf[64 + lane];
  float s = wave_sum(v);
  if (lane == 0){
    scores[row] = s;
    int slot = nb[row] * NENT + ne[row];
    atomicMax(&winner[slot], row);
  }
}

__global__ void __launch_bounds__(256) k_scatter(const float* __restrict__ scores,
    const int* __restrict__ winner, const int* __restrict__ nb, const int* __restrict__ ne,
    float* __restrict__ out, int rows, int NENT){
  int n = blockIdx.x * blockDim.x + threadIdx.x;
  if (n < rows){
    int slot = nb[n] * NENT + ne[n];
    if (winner[slot] == n) out[slot] = scores[n];
  }
}

extern "C" void kernel_launch(void* const* d_in, const int* in_sizes, int n_in,
                              void* d_out, int out_size, void* d_ws, size_t ws_size,
                              hipStream_t stream){
  const float* hidden0 = (const float*)d_in[0];
  const float* rel0    = (const float*)d_in[1];
  const int* batch_idx = (const int*)d_in[2];
  const int* rel_i     = (const int*)d_in[3];
  const int* sub       = (const int*)d_in[4];
  const int* obj       = (const int*)d_in[5];
  const int* q_rel     = (const int*)d_in[6];
  const int* nb        = (const int*)d_in[7];
  const int* ne        = (const int*)d_in[8];
  const float* Ws      = (const float*)d_in[9];
  const float* Wr      = (const float*)d_in[10];
  const float* Wqr_w   = (const float*)d_in[11];
  const float* Wqr_b   = (const float*)d_in[12];
  const float* Wal_w   = (const float*)d_in[13];
  const float* Wal_b   = (const float*)d_in[14];
  const float* Wh      = (const float*)d_in[15];
  const float* rt_w    = (const float*)d_in[16];
  const float* rt_b    = (const float*)d_in[17];
  const float* ln_g    = (const float*)d_in[18];
  const float* ln_b    = (const float*)d_in[19];
  const float* lnr_g   = (const float*)d_in[20];
  const float* lnr_b   = (const float*)d_in[21];
  const float* wih     = (const float*)d_in[22];
  const float* whh     = (const float*)d_in[23];
  const float* bih     = (const float*)d_in[24];
  const float* bhh     = (const float*)d_in[25];
  const float* wfin    = (const float*)d_in[26];

  const int N    = in_sizes[0] / DD;
  const int NR   = in_sizes[1] / DD;
  const int E    = in_sizes[2];
  const int Bc   = in_sizes[6];
  const int L    = in_sizes[14];
  const int Rp1  = NR / Bc;
  const int NENT = out_size / Bc;

  char* wsp = (char*)d_ws;
  auto alloc = [&](size_t bytes) -> void* {
    void* p = (void*)wsp;
    wsp += (bytes + 255) & ~(size_t)255;
    return p;
  };
  float* BUF0    = (float*)alloc((size_t)N * DD * 4);
  float* BUF1    = (float*)alloc((size_t)N * DD * 4);
  float* rel_cur = (float*)alloc((size_t)NR * DD * 4);
  float* hsW     = (float*)alloc((size_t)N * AA * 4);
  float* hrW     = (float*)alloc((size_t)NR * AA * 4);
  float* qr      = (float*)alloc((size_t)Bc * AA * 4);
  float* wihT    = (float*)alloc((size_t)GG * DD * 4);
  float* whhT    = (float*)alloc((size_t)GG * DD * 4);
  float* scores  = (float*)alloc((size_t)N * 4);
  int*   winner  = (int*)alloc((size_t)Bc * NENT * 4);
  (void)ws_size; (void)n_in;

  hipMemcpyAsync(rel_cur, rel0, (size_t)NR * DD * 4, hipMemcpyDeviceToDevice, stream);
  k_transpose<<<(GG*DD + 255)/256, 256, 0, stream>>>(wih, wihT, GG);
  k_transpose<<<(GG*DD + 255)/256, 256, 0, stream>>>(whh, whhT, GG);
  hipMemsetAsync(d_out, 0, (size_t)out_size * 4, stream);
  hipMemsetAsync(winner, 0xFF, (size_t)Bc * NENT * 4, stream);

  const float* hid_in = hidden0;
  const float* hid_prev = nullptr;
  auto wavegrid = [](int waves){ return (waves + 3) / 4; };

  for (int i = 0; i < L; ++i){
    float* agg = (i & 1) ? BUF1 : BUF0;
    k_rel_transfer<<<wavegrid(NR), 256, 0, stream>>>(rel_cur,
        rt_w + (size_t)i*DD*DD, rt_b + (size_t)i*DD,
        lnr_g + (size_t)i*DD, lnr_b + (size_t)i*DD, NR);
    k_proj4<<<wavegrid((N+3)/4), 256, 0, stream>>>(hid_in, Ws + (size_t)i*DD*AA, hsW, N);
    k_proj4<<<wavegrid((NR+3)/4), 256, 0, stream>>>(rel_cur, Wr + (size_t)i*DD*AA, hrW, NR);
    k_projq<<<wavegrid(Bc), 256, 0, stream>>>(rel_cur, Wqr_w + (size_t)i*DD*AA,
        Wqr_b + (size_t)i*AA, q_rel, qr, Bc, Rp1);
    hipMemsetAsync(agg, 0, (size_t)N * DD * 4, stream);
    k_edge<<<8192, 256, 0, stream>>>(hid_in, rel_cur, hsW, hrW, qr,
        Wal_w + (size_t)i*AA, Wal_b + i,
        sub, obj, batch_idx, rel_i, agg, E, Rp1);
    k_wh_ln<<<wavegrid((N+3)/4), 256, 0, stream>>>(agg, Wh + (size_t)i*DD*DD,
        ln_g + (size_t)i*DD, ln_b + (size_t)i*DD, N);
    k_gru4<<<wavegrid((N+3)/4), 256, 0, stream>>>(agg, hid_prev, wihT, whhT, bih, bhh, N);
    k_ln_rows<<<wavegrid(NR), 256, 0, stream>>>(rel_cur,
        lnr_g + (size_t)i*DD, lnr_b + (size_t)i*DD, NR);
    hid_in = agg;
    hid_prev = agg;
  }

  k_score<<<wavegrid(N), 256, 0, stream>>>(hid_in, wfin, nb, ne, scores, winner, N, NENT);
  k_scatter<<<(N + 255)/256, 256, 0, stream>>>(scores, winner, nb, ne, (float*)d_out, N, NENT);
}